// Round 19
// baseline (213.313 us; speedup 1.0000x reference)
//
#include <hip/hip_runtime.h>
#include <hip/hip_bf16.h>

#define M_DIM 8192   // 4 * 2048 rows of x
#define N_DIM 8192   // out_features
#define K_DIM 2048   // in_features (= bytes per int8 row)

#define BK 64                 // int8 elems per K-tile
#define NT (K_DIM / BK)       // 32 K-tiles
#define SLOT_BYTES 16384      // A-only slot: [256 rows][64 B]; 5 slots = 80 KB

typedef float f32x4 __attribute__((ext_vector_type(4)));
typedef int   i32x4 __attribute__((ext_vector_type(4)));
typedef unsigned int u32;
typedef u32 u32x2 __attribute__((ext_vector_type(2)));
typedef u32 u32x4 __attribute__((ext_vector_type(4)));

// ---------- helpers ----------

__device__ __forceinline__ void gload16(const unsigned char* g, char* l) {
    __builtin_amdgcn_global_load_lds(
        (const __attribute__((address_space(1))) u32*)g,
        (__attribute__((address_space(3))) u32*)l, 16, 0, 0);
}

__device__ __forceinline__ u32 pack4(int a, int b, int c, int d) {
    return (u32)(a & 255) | ((u32)(b & 255) << 8) |
           ((u32)(c & 255) << 16) | ((u32)(d & 255) << 24);
}

// ---------- prepass: per-row symmetric int8 quantization of x (row-major) ----------

__global__ void __launch_bounds__(256) quant_x_k(const float* __restrict__ x,
                                                 unsigned char* __restrict__ xq,
                                                 float* __restrict__ sx) {
    const int row = blockIdx.x;
    const int t = threadIdx.x;
    const float* xr = x + (size_t)row * K_DIM;
    f32x4 v0 = *((const f32x4*)xr + t * 2);
    f32x4 v1 = *((const f32x4*)xr + t * 2 + 1);
    float m = fabsf(v0[0]);
    m = fmaxf(m, fabsf(v0[1])); m = fmaxf(m, fabsf(v0[2])); m = fmaxf(m, fabsf(v0[3]));
    m = fmaxf(m, fabsf(v1[0])); m = fmaxf(m, fabsf(v1[1]));
    m = fmaxf(m, fabsf(v1[2])); m = fmaxf(m, fabsf(v1[3]));
#pragma unroll
    for (int off = 32; off >= 1; off >>= 1)
        m = fmaxf(m, __shfl_xor(m, off, 64));
    __shared__ float wmax[4];
    if ((t & 63) == 0) wmax[t >> 6] = m;
    __syncthreads();
    m = fmaxf(fmaxf(wmax[0], wmax[1]), fmaxf(wmax[2], wmax[3]));
    m = fmaxf(m, 1e-20f);
    const float rs = 127.0f / m;
    u32x2 o;
    o[0] = pack4((int)rintf(v0[0] * rs), (int)rintf(v0[1] * rs),
                 (int)rintf(v0[2] * rs), (int)rintf(v0[3] * rs));
    o[1] = pack4((int)rintf(v1[0] * rs), (int)rintf(v1[1] * rs),
                 (int)rintf(v1[2] * rs), (int)rintf(v1[3] * rs));
    *((u32x2*)(xq + (size_t)row * K_DIM) + t) = o;
    if (t == 0) sx[row] = m / 127.0f;
}

// ---------- prepass: int32 weights -> FRAGMENT-MAJOR packed int8 Bt ----------
// Bt[g][kt][lane][16B]: g = 16-col group, kt = K-tile; lane l: fr=l&15 ->
// col g*16+fr, s4=l>>4 -> k bytes kt*64+s4*16. Group stride 32768, kt 1024.

__global__ void __launch_bounds__(256) cvt_w_k(const int* __restrict__ w,
                                               unsigned char* __restrict__ Bt) {
    const int g = blockIdx.x;             // 0..511
    const int t = threadIdx.x;
    const int fr = t >> 4;                // 0..15
    const int kc = t & 15;                // 0..15
    const int col = g * 16 + fr;
    const int* wr = w + (size_t)col * K_DIM + kc * 128;

#pragma unroll
    for (int kk = 0; kk < 8; ++kk) {
        const int k = kc * 128 + kk * 16;
        const int kt = k >> 6;
        const int s4 = (k >> 4) & 3;
        u32x4 o;
#pragma unroll
        for (int j = 0; j < 4; ++j) {
            i32x4 a = *(const i32x4*)(wr + kk * 16 + j * 4);
            o[j] = pack4(a[0], a[1], a[2], a[3]);
        }
        *(u32x4*)(Bt + (size_t)g * 32768 + kt * 1024 + (s4 * 16 + fr) * 16) = o;
    }
}

// ---------- main GEMM: A via LDS (x4 broadcast), B via regs; 2-tile super-body ----------
// r18's race-free 5-slot super-body, with: (1) mid-body VM/LGKM drains removed
// (B loads & ds_reads are C++ loads -> compiler inserts finer counted waits;
// only the global_load_lds publish edge needs the manual top VM4+LGKM0+BAR);
// (2) setprio(1) around MFMA clusters (2 independent blocks/CU -> waves on a
// SIMD are at different phases, the role-diversity T5 needs; m218b mechanism).

__global__ void __launch_bounds__(512, 2)
gemm_i8(const unsigned char* __restrict__ Aq, const unsigned char* __restrict__ Bt,
        const float* __restrict__ sx, const float* __restrict__ sw,
        const float* __restrict__ bias, float* __restrict__ C) {
    extern __shared__ __align__(16) char ldsb[];

    // XCD-bijective swizzle (1024 blocks % 8 == 0)
    const int bid = blockIdx.x;
    const int swz = (bid & 7) * 128 + (bid >> 3);
    const int rowBase = (swz >> 5) * 256;
    const int colBase = (swz & 31) * 256;

    const int t = threadIdx.x;       // 0..511
    const int l = t & 63;
    const int w = t >> 6;
    const int wm = w >> 2;           // 0..1  (128-row half)
    const int wn = w & 3;            // 0..3  (64-col quarter)
    const int fr = l & 15;
    const int s4 = l >> 4;

    // A staging (r16-proven): thread t -> row t>>2 of each half, phys chunk t&3;
    // source k-offset pre-swizzled: logical chunk = phys ^ ((row>>1)&3)
    const int sr = t >> 2;
    const int sk = (((t & 3) ^ ((sr >> 1) & 3)) * 16);
    const unsigned char* gA0 = Aq + (size_t)(rowBase + sr) * K_DIM + sk;
    const unsigned char* gA1 = Aq + (size_t)(rowBase + 128 + sr) * K_DIM + sk;

#define STAGE_A(tk) do { \
        char* _b = ldsb + ((tk) % 5) * SLOT_BYTES; \
        const int _k = (tk) * BK; \
        gload16(gA0 + _k, _b + t * 16); \
        gload16(gA1 + _k, _b + 8192 + t * 16); \
    } while (0)

    // B fragment-major bases
    const unsigned char* bB[4];
#pragma unroll
    for (int ni = 0; ni < 4; ++ni)
        bB[ni] = Bt + (size_t)(colBase / 16 + wn * 4 + ni) * 32768 + l * 16;

#define BLOAD(dst, T) do { \
        _Pragma("unroll") \
        for (int ni = 0; ni < 4; ++ni) \
            dst[ni] = *(const i32x4*)(bB[ni] + (T) * 1024); \
    } while (0)

    // A fragment read offsets within slot: key (row>>1)&3 == (fr>>1)&3
    const int pc = ((s4 ^ ((fr >> 1) & 3)) * 16);
    int aoff[8];
#pragma unroll
    for (int mi = 0; mi < 8; ++mi)
        aoff[mi] = (wm * 128 + mi * 16 + fr) * 64 + pc;

    i32x4 acc[8][4] = {};
    i32x4 afC[8], bf0[4], bf1[4];

#define SBF   __builtin_amdgcn_sched_barrier(0)
#define BAR   __builtin_amdgcn_s_barrier()
#define P1    __builtin_amdgcn_s_setprio(1)
#define P0p   __builtin_amdgcn_s_setprio(0)
#define LGKM0 asm volatile("s_waitcnt lgkmcnt(0)" ::: "memory")
#define VM12  asm volatile("s_waitcnt vmcnt(12)" ::: "memory")
#define VM4   asm volatile("s_waitcnt vmcnt(4)" ::: "memory")
#define VM0   asm volatile("s_waitcnt vmcnt(0)" ::: "memory")

#define READS_A(slot) do { \
        const char* _s = ldsb + (slot) * SLOT_BYTES; \
        _Pragma("unroll") \
        for (int mi = 0; mi < 8; ++mi) afC[mi] = *(const i32x4*)(_s + aoff[mi]); \
    } while (0)

    // interleaved compute: per mi, 4 MFMAs consume afC[mi], then afC[mi] is
    // re-read from slot NSLOT (WAR keeps order; LDS overlaps MFMA).
#define MFMA_ILV(BREG, NSLOT) do { P1; \
        const char* _n = ldsb + (NSLOT) * SLOT_BYTES; \
        _Pragma("unroll") \
        for (int mi = 0; mi < 8; ++mi) { \
            _Pragma("unroll") \
            for (int ni = 0; ni < 4; ++ni) \
                acc[mi][ni] = __builtin_amdgcn_mfma_i32_16x16x64_i8( \
                    afC[mi], BREG[ni], acc[mi][ni], 0, 0, 0); \
            afC[mi] = *(const i32x4*)(_n + aoff[mi]); \
        } \
        P0p; } while (0)

#define MFMA_ALL(BREG) do { P1; \
        _Pragma("unroll") \
        for (int mi = 0; mi < 8; ++mi) \
            _Pragma("unroll") \
            for (int ni = 0; ni < 4; ++ni) \
                acc[mi][ni] = __builtin_amdgcn_mfma_i32_16x16x64_i8( \
                    afC[mi], BREG[ni], acc[mi][ni], 0, 0, 0); \
        P0p; } while (0)

    // super-body: consumes tiles {T,T+1}; stages A(T+4),A(T+5) AFTER the BAR
    // (race-fix, r18); loads B(T+2),B(T+3) mid-body with compiler-counted waits.
    // Top VM4 forces {A(T+2),A(T+3),B(T)} (gload_lds publish edge needs manual
    // vmcnt); LGKM0 drains afC re-reads of slot (T+2)%5 before the BAR that
    // precedes its overwrite next SB.
#define SBODY(T, DOSTG) do { \
        VM4; LGKM0; SBF; BAR; SBF; \
        if (DOSTG) { STAGE_A((T) + 4); STAGE_A((T) + 5); } \
        MFMA_ILV(bf0, ((T) + 1) % 5); \
        BLOAD(bf0, (T) + 2); \
        MFMA_ILV(bf1, ((T) + 2) % 5); \
        BLOAD(bf1, (T) + 3); \
    } while (0)

    // prologue: A0-A3 staged (8 ops), B0,B1 loaded (8 ops);
    // VM(12) forces A0,A1 (leaves {A2,A3,B0,B1}=12 = induction base); BAR.
    STAGE_A(0); STAGE_A(1); STAGE_A(2); STAGE_A(3);
    BLOAD(bf0, 0); BLOAD(bf1, 1);
    VM12; SBF; BAR; SBF;
    READS_A(0);

    // SB chain: tiles 0..27 with stages; tiles 28,29 without.
    SBODY(0,  true);  SBODY(2,  true);  SBODY(4,  true);
    SBODY(6,  true);  SBODY(8,  true);  SBODY(10, true);
    SBODY(12, true);  SBODY(14, true);  SBODY(16, true);
    SBODY(18, true);  SBODY(20, true);  SBODY(22, true);
    SBODY(24, true);  SBODY(26, true);
    SBODY(28, false);

    // tail (tiles 30,31): slot 1 (tile 31) was forced at SBODY(28)'s top VM4
    // and published by its BAR. B30/B31 waits are compiler-counted; VM0/LGKM0
    // kept once for safety.
    VM0; LGKM0; SBF;
    MFMA_ILV(bf0, 31 % 5);             // tile 30; re-reads tile 31 (slot 1)
    MFMA_ALL(bf1);                     // tile 31

#undef SBODY
#undef MFMA_ALL
#undef MFMA_ILV
#undef READS_A
#undef BLOAD
#undef STAGE_A

    // epilogue: C/D layout col=lane&15, row=(lane>>4)*4+reg (proven r7)
    // out = acc_i32 * sx[row] * sw[col] + bias[col]
#pragma unroll
    for (int ni = 0; ni < 4; ++ni) {
        const int col = colBase + wn * 64 + ni * 16 + fr;
        const float swc = sw[col];
        const float bz = bias[col];
#pragma unroll
        for (int mi = 0; mi < 8; ++mi) {
            const int rb = rowBase + wm * 128 + mi * 16 + s4 * 4;
            i32x4 a = acc[mi][ni];
#pragma unroll
            for (int r = 0; r < 4; ++r)
                C[(size_t)(rb + r) * N_DIM + col] =
                    (float)a[r] * (sx[rb + r] * swc) + bz;
        }
    }
}

// ---------- correctness fallback if workspace too small (should not trigger) ----------

typedef int i32x4_t __attribute__((ext_vector_type(4)));
__global__ void __launch_bounds__(256) naive_k(const float* __restrict__ x,
                                               const int* __restrict__ w,
                                               const float* __restrict__ scale,
                                               const float* __restrict__ bias,
                                               float* __restrict__ out) {
    __shared__ float xs[K_DIM];
    const int m = blockIdx.x >> 5;
    const int n = ((blockIdx.x & 31) << 8) + threadIdx.x;
    for (int i = threadIdx.x; i < K_DIM; i += 256) xs[i] = x[(size_t)m * K_DIM + i];
    __syncthreads();
    const int* wr = w + (size_t)n * K_DIM;
    float acc = 0.f;
    for (int k = 0; k < K_DIM; k += 4) {
        i32x4_t v = *(const i32x4_t*)(wr + k);
        acc += xs[k]     * (float)v[0];
        acc += xs[k + 1] * (float)v[1];
        acc += xs[k + 2] * (float)v[2];
        acc += xs[k + 3] * (float)v[3];
    }
    out[(size_t)m * N_DIM + n] = acc * scale[n] + bias[n];
}

// ---------- launch ----------

extern "C" void kernel_launch(void* const* d_in, const int* in_sizes, int n_in,
                              void* d_out, int out_size, void* d_ws, size_t ws_size,
                              hipStream_t stream) {
    const float* x     = (const float*)d_in[0];
    const int*   w8    = (const int*)d_in[1];   // int8 values stored as int32
    const float* sw    = (const float*)d_in[2];
    const float* bias  = (const float*)d_in[3];
    float*       out   = (float*)d_out;

    const size_t xq_bytes = (size_t)M_DIM * K_DIM;          // 16 MB
    const size_t wq_bytes = (size_t)N_DIM * K_DIM;          // 16 MB
    const size_t need = xq_bytes + wq_bytes + (size_t)M_DIM * sizeof(float);
    if (ws_size >= need) {
        unsigned char* xq = (unsigned char*)d_ws;
        unsigned char* Bt = xq + xq_bytes;
        float* sx = (float*)(Bt + wq_bytes);
        hipFuncSetAttribute((const void*)gemm_i8,
                            hipFuncAttributeMaxDynamicSharedMemorySize, 5 * SLOT_BYTES);
        quant_x_k<<<M_DIM, 256, 0, stream>>>(x, xq, sx);
        cvt_w_k<<<N_DIM / 16, 256, 0, stream>>>(w8, Bt);
        gemm_i8<<<dim3((M_DIM / 256) * (N_DIM / 256)), 512, 5 * SLOT_BYTES, stream>>>(
            xq, Bt, sx, sw, bias, out);
    } else {
        naive_k<<<(M_DIM * (N_DIM / 256)), 256, 0, stream>>>(x, w8, sw, bias, out);
    }
}

// Round 20
// 203.505 us; speedup vs baseline: 1.0482x; 1.0482x over previous
//
#include <hip/hip_runtime.h>
#include <hip/hip_bf16.h>

#define M_DIM 8192   // 4 * 2048 rows of x
#define N_DIM 8192   // out_features
#define K_DIM 2048   // in_features (= bytes per int8 row)

#define BK 64                 // int8 elems per K-tile
#define NT (K_DIM / BK)       // 32 K-tiles
#define SLOT_BYTES 16384      // A-only slot: [256 rows][64 B]; 5 slots = 80 KB

typedef float f32x4 __attribute__((ext_vector_type(4)));
typedef int   i32x4 __attribute__((ext_vector_type(4)));
typedef unsigned int u32;
typedef u32 u32x2 __attribute__((ext_vector_type(2)));
typedef u32 u32x4 __attribute__((ext_vector_type(4)));

// ---------- helpers ----------

__device__ __forceinline__ void gload16(const unsigned char* g, char* l) {
    __builtin_amdgcn_global_load_lds(
        (const __attribute__((address_space(1))) u32*)g,
        (__attribute__((address_space(3))) u32*)l, 16, 0, 0);
}

__device__ __forceinline__ u32 pack4(int a, int b, int c, int d) {
    return (u32)(a & 255) | ((u32)(b & 255) << 8) |
           ((u32)(c & 255) << 16) | ((u32)(d & 255) << 24);
}

// ---------- prepass: per-row symmetric int8 quantization of x (row-major) ----------

__global__ void __launch_bounds__(256) quant_x_k(const float* __restrict__ x,
                                                 unsigned char* __restrict__ xq,
                                                 float* __restrict__ sx) {
    const int row = blockIdx.x;
    const int t = threadIdx.x;
    const float* xr = x + (size_t)row * K_DIM;
    f32x4 v0 = *((const f32x4*)xr + t * 2);
    f32x4 v1 = *((const f32x4*)xr + t * 2 + 1);
    float m = fabsf(v0[0]);
    m = fmaxf(m, fabsf(v0[1])); m = fmaxf(m, fabsf(v0[2])); m = fmaxf(m, fabsf(v0[3]));
    m = fmaxf(m, fabsf(v1[0])); m = fmaxf(m, fabsf(v1[1]));
    m = fmaxf(m, fabsf(v1[2])); m = fmaxf(m, fabsf(v1[3]));
#pragma unroll
    for (int off = 32; off >= 1; off >>= 1)
        m = fmaxf(m, __shfl_xor(m, off, 64));
    __shared__ float wmax[4];
    if ((t & 63) == 0) wmax[t >> 6] = m;
    __syncthreads();
    m = fmaxf(fmaxf(wmax[0], wmax[1]), fmaxf(wmax[2], wmax[3]));
    m = fmaxf(m, 1e-20f);
    const float rs = 127.0f / m;
    u32x2 o;
    o[0] = pack4((int)rintf(v0[0] * rs), (int)rintf(v0[1] * rs),
                 (int)rintf(v0[2] * rs), (int)rintf(v0[3] * rs));
    o[1] = pack4((int)rintf(v1[0] * rs), (int)rintf(v1[1] * rs),
                 (int)rintf(v1[2] * rs), (int)rintf(v1[3] * rs));
    *((u32x2*)(xq + (size_t)row * K_DIM) + t) = o;
    if (t == 0) sx[row] = m / 127.0f;
}

// ---------- prepass: int32 weights -> FRAGMENT-MAJOR packed int8 Bt ----------
// Bt[g][kt][lane][16B]: g = 16-col group, kt = K-tile; lane l: fr=l&15 ->
// col g*16+fr, s4=l>>4 -> k bytes kt*64+s4*16. Group stride 32768, kt 1024.

__global__ void __launch_bounds__(256) cvt_w_k(const int* __restrict__ w,
                                               unsigned char* __restrict__ Bt) {
    const int g = blockIdx.x;             // 0..511
    const int t = threadIdx.x;
    const int fr = t >> 4;                // 0..15
    const int kc = t & 15;                // 0..15
    const int col = g * 16 + fr;
    const int* wr = w + (size_t)col * K_DIM + kc * 128;

#pragma unroll
    for (int kk = 0; kk < 8; ++kk) {
        const int k = kc * 128 + kk * 16;
        const int kt = k >> 6;
        const int s4 = (k >> 4) & 3;
        u32x4 o;
#pragma unroll
        for (int j = 0; j < 4; ++j) {
            i32x4 a = *(const i32x4*)(wr + kk * 16 + j * 4);
            o[j] = pack4(a[0], a[1], a[2], a[3]);
        }
        *(u32x4*)(Bt + (size_t)g * 32768 + kt * 1024 + (s4 * 16 + fr) * 16) = o;
    }
}

// ---------- main GEMM: A via LDS (x4 broadcast), B via regs; 2-tile super-body ----------
// r18 verbatim (best verified: gemm 180.5us, total 204.7us). Race-free 5-slot
// super-body: stages issued AFTER the barrier -> any write is ordered after all
// waves' prior reads (LGKM0-drained at arrival). 5 slots = 80KB -> 2 blocks/CU.
// SBODY(T) consumes tiles {T,T+1}: VM(4) forces {A(T+2),A(T+3),B(T)} pre-BAR
// (publishes both slots read this SB); BAR; stage A(T+4),A(T+5); ILV tile T
// (re-reads T+1); BLOAD B(T+2); VM(8) forces B(T+1) (reg-only, no BAR needed);
// ILV tile T+1 (re-reads T+2); BLOAD B(T+3). 1 barrier per 64 MFMA. No setprio
// (m190 + r19 A/B: hurts this lockstep structure).

__global__ void __launch_bounds__(512, 2)
gemm_i8(const unsigned char* __restrict__ Aq, const unsigned char* __restrict__ Bt,
        const float* __restrict__ sx, const float* __restrict__ sw,
        const float* __restrict__ bias, float* __restrict__ C) {
    extern __shared__ __align__(16) char ldsb[];

    // XCD-bijective swizzle (1024 blocks % 8 == 0)
    const int bid = blockIdx.x;
    const int swz = (bid & 7) * 128 + (bid >> 3);
    const int rowBase = (swz >> 5) * 256;
    const int colBase = (swz & 31) * 256;

    const int t = threadIdx.x;       // 0..511
    const int l = t & 63;
    const int w = t >> 6;
    const int wm = w >> 2;           // 0..1  (128-row half)
    const int wn = w & 3;            // 0..3  (64-col quarter)
    const int fr = l & 15;
    const int s4 = l >> 4;

    // A staging (r16-proven): thread t -> row t>>2 of each half, phys chunk t&3;
    // source k-offset pre-swizzled: logical chunk = phys ^ ((row>>1)&3)
    const int sr = t >> 2;
    const int sk = (((t & 3) ^ ((sr >> 1) & 3)) * 16);
    const unsigned char* gA0 = Aq + (size_t)(rowBase + sr) * K_DIM + sk;
    const unsigned char* gA1 = Aq + (size_t)(rowBase + 128 + sr) * K_DIM + sk;

#define STAGE_A(tk) do { \
        char* _b = ldsb + ((tk) % 5) * SLOT_BYTES; \
        const int _k = (tk) * BK; \
        gload16(gA0 + _k, _b + t * 16); \
        gload16(gA1 + _k, _b + 8192 + t * 16); \
    } while (0)

    // B fragment-major bases
    const unsigned char* bB[4];
#pragma unroll
    for (int ni = 0; ni < 4; ++ni)
        bB[ni] = Bt + (size_t)(colBase / 16 + wn * 4 + ni) * 32768 + l * 16;

#define BLOAD(dst, T) do { \
        _Pragma("unroll") \
        for (int ni = 0; ni < 4; ++ni) \
            dst[ni] = *(const i32x4*)(bB[ni] + (T) * 1024); \
    } while (0)

    // A fragment read offsets within slot: key (row>>1)&3 == (fr>>1)&3
    const int pc = ((s4 ^ ((fr >> 1) & 3)) * 16);
    int aoff[8];
#pragma unroll
    for (int mi = 0; mi < 8; ++mi)
        aoff[mi] = (wm * 128 + mi * 16 + fr) * 64 + pc;

    i32x4 acc[8][4] = {};
    i32x4 afC[8], bf0[4], bf1[4];

#define SBF   __builtin_amdgcn_sched_barrier(0)
#define BAR   __builtin_amdgcn_s_barrier()
#define LGKM0 asm volatile("s_waitcnt lgkmcnt(0)" ::: "memory")
#define VM12  asm volatile("s_waitcnt vmcnt(12)" ::: "memory")
#define VM8   asm volatile("s_waitcnt vmcnt(8)" ::: "memory")
#define VM4   asm volatile("s_waitcnt vmcnt(4)" ::: "memory")
#define VM0   asm volatile("s_waitcnt vmcnt(0)" ::: "memory")

#define READS_A(slot) do { \
        const char* _s = ldsb + (slot) * SLOT_BYTES; \
        _Pragma("unroll") \
        for (int mi = 0; mi < 8; ++mi) afC[mi] = *(const i32x4*)(_s + aoff[mi]); \
    } while (0)

    // interleaved compute: per mi, 4 MFMAs consume afC[mi], then afC[mi] is
    // re-read from slot NSLOT (WAR keeps order; LDS overlaps MFMA).
#define MFMA_ILV(BREG, NSLOT) do { \
        const char* _n = ldsb + (NSLOT) * SLOT_BYTES; \
        _Pragma("unroll") \
        for (int mi = 0; mi < 8; ++mi) { \
            _Pragma("unroll") \
            for (int ni = 0; ni < 4; ++ni) \
                acc[mi][ni] = __builtin_amdgcn_mfma_i32_16x16x64_i8( \
                    afC[mi], BREG[ni], acc[mi][ni], 0, 0, 0); \
            afC[mi] = *(const i32x4*)(_n + aoff[mi]); \
        } \
    } while (0)

#define MFMA_ALL(BREG) do { \
        _Pragma("unroll") \
        for (int mi = 0; mi < 8; ++mi) \
            _Pragma("unroll") \
            for (int ni = 0; ni < 4; ++ni) \
                acc[mi][ni] = __builtin_amdgcn_mfma_i32_16x16x64_i8( \
                    afC[mi], BREG[ni], acc[mi][ni], 0, 0, 0); \
    } while (0)

    // super-body: consumes tiles {T,T+1}; stages A(T+4),A(T+5) AFTER the BAR
    // (race-fix); loads B(T+2),B(T+3) mid-body.
#define SBODY(T, DOSTG, VMMID) do { \
        VM4; LGKM0; SBF; BAR; SBF; \
        if (DOSTG) { STAGE_A((T) + 4); STAGE_A((T) + 5); } \
        MFMA_ILV(bf0, ((T) + 1) % 5); \
        BLOAD(bf0, (T) + 2); \
        VMMID; LGKM0; SBF; \
        MFMA_ILV(bf1, ((T) + 2) % 5); \
        BLOAD(bf1, (T) + 3); \
    } while (0)

    // prologue: A0-A3 staged (8 ops), B0,B1 loaded (8 ops);
    // VM(12) forces A0,A1 (leaves {A2,A3,B0,B1}=12 = induction base); BAR.
    STAGE_A(0); STAGE_A(1); STAGE_A(2); STAGE_A(3);
    BLOAD(bf0, 0); BLOAD(bf1, 1);
    VM12; SBF; BAR; SBF;
    READS_A(0);

    // SB chain: tiles 0..27 with stages; tiles 28,29 without.
    SBODY(0,  true, VM8);  SBODY(2,  true, VM8);  SBODY(4,  true, VM8);
    SBODY(6,  true, VM8);  SBODY(8,  true, VM8);  SBODY(10, true, VM8);
    SBODY(12, true, VM8);  SBODY(14, true, VM8);  SBODY(16, true, VM8);
    SBODY(18, true, VM8);  SBODY(20, true, VM8);  SBODY(22, true, VM8);
    SBODY(24, true, VM8);  SBODY(26, true, VM8);
    SBODY(28, false, VM4);             // mid queue {B29,B30}=8 -> VM4 forces B29

    // tail (tiles 30,31): outstanding {B30,B31}=8. Slot 1 (tile 31) was forced
    // at SBODY(28)'s top VM4 and published by its BAR.
    VM4; LGKM0; SBF;                   // forces B30
    MFMA_ILV(bf0, 31 % 5);             // tile 30; re-reads tile 31 (slot 1)
    VM0; LGKM0; SBF;                   // forces B31; drains re-reads
    MFMA_ALL(bf1);                     // tile 31

#undef SBODY
#undef MFMA_ALL
#undef MFMA_ILV
#undef READS_A
#undef BLOAD
#undef STAGE_A

    // epilogue: C/D layout col=lane&15, row=(lane>>4)*4+reg (proven r7)
    // out = acc_i32 * sx[row] * sw[col] + bias[col]
#pragma unroll
    for (int ni = 0; ni < 4; ++ni) {
        const int col = colBase + wn * 64 + ni * 16 + fr;
        const float swc = sw[col];
        const float bz = bias[col];
#pragma unroll
        for (int mi = 0; mi < 8; ++mi) {
            const int rb = rowBase + wm * 128 + mi * 16 + s4 * 4;
            i32x4 a = acc[mi][ni];
#pragma unroll
            for (int r = 0; r < 4; ++r)
                C[(size_t)(rb + r) * N_DIM + col] =
                    (float)a[r] * (sx[rb + r] * swc) + bz;
        }
    }
}

// ---------- correctness fallback if workspace too small (should not trigger) ----------

typedef int i32x4_t __attribute__((ext_vector_type(4)));
__global__ void __launch_bounds__(256) naive_k(const float* __restrict__ x,
                                               const int* __restrict__ w,
                                               const float* __restrict__ scale,
                                               const float* __restrict__ bias,
                                               float* __restrict__ out) {
    __shared__ float xs[K_DIM];
    const int m = blockIdx.x >> 5;
    const int n = ((blockIdx.x & 31) << 8) + threadIdx.x;
    for (int i = threadIdx.x; i < K_DIM; i += 256) xs[i] = x[(size_t)m * K_DIM + i];
    __syncthreads();
    const int* wr = w + (size_t)n * K_DIM;
    float acc = 0.f;
    for (int k = 0; k < K_DIM; k += 4) {
        i32x4_t v = *(const i32x4_t*)(wr + k);
        acc += xs[k]     * (float)v[0];
        acc += xs[k + 1] * (float)v[1];
        acc += xs[k + 2] * (float)v[2];
        acc += xs[k + 3] * (float)v[3];
    }
    out[(size_t)m * N_DIM + n] = acc * scale[n] + bias[n];
}

// ---------- launch ----------

extern "C" void kernel_launch(void* const* d_in, const int* in_sizes, int n_in,
                              void* d_out, int out_size, void* d_ws, size_t ws_size,
                              hipStream_t stream) {
    const float* x     = (const float*)d_in[0];
    const int*   w8    = (const int*)d_in[1];   // int8 values stored as int32
    const float* sw    = (const float*)d_in[2];
    const float* bias  = (const float*)d_in[3];
    float*       out   = (float*)d_out;

    const size_t xq_bytes = (size_t)M_DIM * K_DIM;          // 16 MB
    const size_t wq_bytes = (size_t)N_DIM * K_DIM;          // 16 MB
    const size_t need = xq_bytes + wq_bytes + (size_t)M_DIM * sizeof(float);
    if (ws_size >= need) {
        unsigned char* xq = (unsigned char*)d_ws;
        unsigned char* Bt = xq + xq_bytes;
        float* sx = (float*)(Bt + wq_bytes);
        hipFuncSetAttribute((const void*)gemm_i8,
                            hipFuncAttributeMaxDynamicSharedMemorySize, 5 * SLOT_BYTES);
        quant_x_k<<<M_DIM, 256, 0, stream>>>(x, xq, sx);
        cvt_w_k<<<N_DIM / 16, 256, 0, stream>>>(w8, Bt);
        gemm_i8<<<dim3((M_DIM / 256) * (N_DIM / 256)), 512, 5 * SLOT_BYTES, stream>>>(
            xq, Bt, sx, sw, bias, out);
    } else {
        naive_k<<<(M_DIM * (N_DIM / 256)), 256, 0, stream>>>(x, w8, sw, bias, out);
    }
}